// Round 6
// baseline (672.131 us; speedup 1.0000x reference)
//
#include <hip/hip_runtime.h>
#include <hip/hip_bf16.h>
#include <stdint.h>

#define DIN   1024
#define DOUT  1024
#define NHEAD 16
#define HDIM  64
#define SEQL  2048
#define BSZ   4
#define MTOT  (BSZ*SEQL)   // 8192
#define KDIM  1024

typedef __bf16 bf16x8 __attribute__((ext_vector_type(8)));
typedef float  f32x4  __attribute__((ext_vector_type(4)));

__device__ __forceinline__ f32x4 mfma16(bf16x8 a, bf16x8 b, f32x4 c) {
    return __builtin_amdgcn_mfma_f32_16x16x32_bf16(a, b, c, 0, 0, 0);
}

__device__ __forceinline__ void gl_lds16(const void* gsrc, void* ldst) {
    __builtin_amdgcn_global_load_lds(
        (const __attribute__((address_space(1))) uint32_t*)gsrc,
        (__attribute__((address_space(3))) uint32_t*)ldst, 16, 0, 0);
}

__device__ __forceinline__ unsigned short f2bf(float f) {
    union { __hip_bfloat16 h; unsigned short u; } cv;
    cv.h = __float2bfloat16(f);
    return cv.u;
}

// ---------------- fp32 -> bf16 elementwise (vectorized) ----------------
__global__ void cvt_bf16(const float4* __restrict__ in, ushort4* __restrict__ out, int n4) {
    int idx = blockIdx.x * blockDim.x + threadIdx.x;
    int stride = gridDim.x * blockDim.x;
    for (int i = idx; i < n4; i += stride) {
        float4 v = in[i];
        ushort4 o;
        o.x = f2bf(v.x); o.y = f2bf(v.y); o.z = f2bf(v.z); o.w = f2bf(v.w);
        out[i] = o;
    }
}

// ---- transpose + convert 3x W[1024][1024] f32 -> one Wt3[3072][1024] bf16 ----
__global__ void transpose_cvt3(const float* __restrict__ W0, const float* __restrict__ W1,
                               const float* __restrict__ W2, __hip_bfloat16* __restrict__ Wt3) {
    __shared__ __hip_bfloat16 t[32][33];
    const int tx = threadIdx.x, ty = threadIdx.y;   // (32, 8)
    const int bx = blockIdx.x, by = blockIdx.y, z = blockIdx.z;
    const float* W = (z == 0) ? W0 : (z == 1) ? W1 : W2;
    __hip_bfloat16* Wt = Wt3 + (size_t)z * DOUT * DIN;
#pragma unroll
    for (int r = 0; r < 4; ++r)
        t[ty + 8*r][tx] = __float2bfloat16(W[(size_t)(by*32 + ty + 8*r) * DOUT + bx*32 + tx]);
    __syncthreads();
#pragma unroll
    for (int r = 0; r < 4; ++r)
        Wt[(size_t)(bx*32 + ty + 8*r) * DIN + by*32 + tx] = t[tx][ty + 8*r];
}

__global__ void transpose_cvt(const float* __restrict__ W, __hip_bfloat16* __restrict__ Wt) {
    __shared__ __hip_bfloat16 t[32][33];
    const int tx = threadIdx.x, ty = threadIdx.y;
    const int bx = blockIdx.x, by = blockIdx.y;
#pragma unroll
    for (int r = 0; r < 4; ++r)
        t[ty + 8*r][tx] = __float2bfloat16(W[(size_t)(by*32 + ty + 8*r) * DOUT + bx*32 + tx]);
    __syncthreads();
#pragma unroll
    for (int r = 0; r < 4; ++r)
        Wt[(size_t)(bx*32 + ty + 8*r) * DIN + by*32 + tx] = t[tx][ty + 8*r];
}

// ---------------- fused QKV GEMM: 256x256 tile, 8 waves, BK=32, 2-phase ----------------
// C = x[8192,1024] * Wt3[3072,1024]^T.  N-slabs: [0,1024)=Q (swapped mfma -> C^T,
// packed d-stores, *scale), [1024,2048)=K (same, no scale), [2048,3072)=V (normal
// mfma, packed seq-stores into V^T [B,H,64,S]).
// NOTE: no min-waves bound -- acc[8][4] alone is 128 VGPRs; capping at 128 (R5,
// __launch_bounds__(512,2)) spilled accumulators to scratch (1.09 GB WRITE_SIZE).
__global__ __launch_bounds__(512)
void gemm_qkv256(const __hip_bfloat16* __restrict__ A,
                 const __hip_bfloat16* __restrict__ Bt,
                 const float* __restrict__ bq, const float* __restrict__ bk,
                 const float* __restrict__ bv,
                 __hip_bfloat16* __restrict__ Qo, __hip_bfloat16* __restrict__ Ko,
                 __hip_bfloat16* __restrict__ Vo,
                 float qscale)
{
    __shared__ alignas(16) __hip_bfloat16 As[2][4][256][8];   // 32 KB
    __shared__ alignas(16) __hip_bfloat16 Bs[2][4][256][8];   // 32 KB

    const int tid  = threadIdx.x;
    const int w    = tid >> 6;        // 0..7
    const int lane = tid & 63;
    const int g    = lane >> 4;
    const int r    = lane & 15;
    const int wr   = w >> 2;          // 0..1 (M half)
    const int wc   = w & 3;           // 0..3 (N quarter)
    const int sg   = w & 3;           // staging k-group
    const int sb   = w >> 2;          // staging row-half

    const int row0 = blockIdx.y * 256;
    const int col0 = blockIdx.x * 256;
    const bool vslab = (col0 >= 2048);

    f32x4 acc[8][4];
#pragma unroll
    for (int m = 0; m < 8; ++m)
#pragma unroll
        for (int n = 0; n < 4; ++n) acc[m][n] = (f32x4)0.0f;

    auto stage = [&](int buf, int kt) {
        const __hip_bfloat16* ga = A  + (size_t)(row0 + sb*128 + lane) * KDIM + kt*32 + 8*sg;
        const __hip_bfloat16* gb = Bt + (size_t)(col0 + sb*128 + lane) * KDIM + kt*32 + 8*sg;
        gl_lds16(ga,           &As[buf][sg][sb*128     ][0]);
        gl_lds16(ga + 64*KDIM, &As[buf][sg][sb*128 + 64][0]);
        gl_lds16(gb,           &Bs[buf][sg][sb*128     ][0]);
        gl_lds16(gb + 64*KDIM, &Bs[buf][sg][sb*128 + 64][0]);
    };

    stage(0, 0);
    __syncthreads();

    const int NKT = KDIM / 32;
    for (int kt = 0; kt < NKT; ++kt) {
        const int cur = kt & 1;
        if (kt + 1 < NKT) stage(cur ^ 1, kt + 1);

        bf16x8 af[8], bfr[4];
#pragma unroll
        for (int m = 0; m < 8; ++m)
            af[m] = *reinterpret_cast<const bf16x8*>(&As[cur][g][wr*128 + 16*m + r][0]);
#pragma unroll
        for (int n = 0; n < 4; ++n)
            bfr[n] = *reinterpret_cast<const bf16x8*>(&Bs[cur][g][wc*64 + 16*n + r][0]);

        if (!vslab) {
#pragma unroll
            for (int m = 0; m < 8; ++m)
#pragma unroll
                for (int n = 0; n < 4; ++n)
                    acc[m][n] = mfma16(bfr[n], af[m], acc[m][n]);   // C^T
        } else {
#pragma unroll
            for (int m = 0; m < 8; ++m)
#pragma unroll
                for (int n = 0; n < 4; ++n)
                    acc[m][n] = mfma16(af[m], bfr[n], acc[m][n]);   // C
        }

        __syncthreads();
    }

    if (!vslab) {
        // C^T frag: lane row (r) = seq row; regs j = 4 consecutive d-cols
        const int slab = col0 >> 10;            // 0=Q, 1=K (block-uniform)
        const float* bp = (slab == 0) ? bq : bk;
        __hip_bfloat16* op = (slab == 0) ? Qo : Ko;
        const float sc = (slab == 0) ? qscale : 1.0f;
#pragma unroll
        for (int m = 0; m < 8; ++m) {
            const int rowg = row0 + wr*128 + 16*m + r;
            const int bb = rowg >> 11, sq = rowg & (SEQL-1);
#pragma unroll
            for (int n = 0; n < 4; ++n) {
                const int c2 = (col0 & 1023) + wc*64 + 16*n + 4*g;
                const int hh = c2 >> 6, dd = c2 & (HDIM-1);
                const float4 bv4 = *reinterpret_cast<const float4*>(&bp[c2]);
                ushort4 ov;
                ov.x = f2bf((acc[m][n][0] + bv4.x) * sc);
                ov.y = f2bf((acc[m][n][1] + bv4.y) * sc);
                ov.z = f2bf((acc[m][n][2] + bv4.z) * sc);
                ov.w = f2bf((acc[m][n][3] + bv4.w) * sc);
                *reinterpret_cast<ushort4*>(
                    &op[(((size_t)(bb*NHEAD + hh) * SEQL + sq) << 6) + dd]) = ov;
            }
        }
    } else {
        // C frag: lane col (r) = d; regs j = 4 consecutive seq rows -> V^T contiguous
#pragma unroll
        for (int n = 0; n < 4; ++n) {
            const int colg = (col0 - 2048) + wc*64 + 16*n + r;
            const int hh = colg >> 6, dd = colg & (HDIM-1);
            const float bvv = bv[colg];
#pragma unroll
            for (int m = 0; m < 8; ++m) {
                const int rowg0 = row0 + wr*128 + 16*m + 4*g;
                const int bb = rowg0 >> 11, sq0 = rowg0 & (SEQL-1);
                ushort4 ov;
                ov.x = f2bf(acc[m][n][0] + bvv);
                ov.y = f2bf(acc[m][n][1] + bvv);
                ov.z = f2bf(acc[m][n][2] + bvv);
                ov.w = f2bf(acc[m][n][3] + bvv);
                *reinterpret_cast<ushort4*>(
                    &Vo[((size_t)(bb*NHEAD + hh) * HDIM + dd) * SEQL + sq0]) = ov;
            }
        }
    }
}

// ---------------- out-proj GEMM: 128x128 tile, swapped mfma, f32x4 stores ----------------
__global__ __launch_bounds__(256)
void gemm_out128(const __hip_bfloat16* __restrict__ A,
                 const __hip_bfloat16* __restrict__ Bt,
                 const float* __restrict__ b0,
                 float* __restrict__ o0)
{
    __shared__ alignas(16) __hip_bfloat16 As[2][4][128][8];
    __shared__ alignas(16) __hip_bfloat16 Bs[2][4][128][8];

    const int tid  = threadIdx.x;
    const int w    = tid >> 6;
    const int lane = tid & 63;
    const int g    = lane >> 4;
    const int r    = lane & 15;
    const int wr   = w >> 1, wc = w & 1;

    const int row0 = blockIdx.y * 128;
    const int col0 = blockIdx.x * 128;

    f32x4 acc[4][4];
#pragma unroll
    for (int m = 0; m < 4; ++m)
#pragma unroll
        for (int n = 0; n < 4; ++n) acc[m][n] = (f32x4)0.0f;

    auto stage = [&](int buf, int kt) {
        const __hip_bfloat16* ga = A  + (size_t)(row0 + lane) * KDIM + kt*32 + 8*w;
        const __hip_bfloat16* gb = Bt + (size_t)(col0 + lane) * KDIM + kt*32 + 8*w;
        gl_lds16(ga,            &As[buf][w][0][0]);
        gl_lds16(ga + 64*KDIM,  &As[buf][w][64][0]);
        gl_lds16(gb,            &Bs[buf][w][0][0]);
        gl_lds16(gb + 64*KDIM,  &Bs[buf][w][64][0]);
    };

    stage(0, 0);
    __syncthreads();

    const int NKT = KDIM / 32;
    for (int kt = 0; kt < NKT; ++kt) {
        const int cur = kt & 1;
        if (kt + 1 < NKT) stage(cur ^ 1, kt + 1);

        bf16x8 af[4], bfr[4];
#pragma unroll
        for (int m = 0; m < 4; ++m)
            af[m] = *reinterpret_cast<const bf16x8*>(&As[cur][g][64*wr + 16*m + r][0]);
#pragma unroll
        for (int n = 0; n < 4; ++n)
            bfr[n] = *reinterpret_cast<const bf16x8*>(&Bs[cur][g][64*wc + 16*n + r][0]);

#pragma unroll
        for (int m = 0; m < 4; ++m)
#pragma unroll
            for (int n = 0; n < 4; ++n)
                acc[m][n] = mfma16(bfr[n], af[m], acc[m][n]);   // C^T

        __syncthreads();
    }

#pragma unroll
    for (int m = 0; m < 4; ++m) {
        const int rowg = row0 + 64*wr + 16*m + r;
#pragma unroll
        for (int n = 0; n < 4; ++n) {
            const int colg0 = col0 + 64*wc + 16*n + 4*g;
            const float4 bv4 = *reinterpret_cast<const float4*>(&b0[colg0]);
            float4 ov;
            ov.x = acc[m][n][0] + bv4.x;
            ov.y = acc[m][n][1] + bv4.y;
            ov.z = acc[m][n][2] + bv4.z;
            ov.w = acc[m][n][3] + bv4.w;
            *reinterpret_cast<float4*>(&o0[(size_t)rowg * DOUT + colg0]) = ov;
        }
    }
}

// ---------------- causal flash attention (swapped-operand, 32 rows/wave) ----------------
// Q,K: [B,H,S,64] bf16 (Q pre-scaled by log2e/8).  Vt: [B,H,64,S] bf16.
// ctx out: [B,S,H*64] bf16.
// 4 waves/block; each wave owns 32-row strip pair (sp, 63-sp) for causal balance.
__global__ __launch_bounds__(256)
void attn_fwd(const __hip_bfloat16* __restrict__ Q,
              const __hip_bfloat16* __restrict__ K,
              const __hip_bfloat16* __restrict__ Vt,
              __hip_bfloat16* __restrict__ ctx)
{
    __shared__ alignas(16) __hip_bfloat16 Ps[4][2][16][64];

    const int tid  = threadIdx.x;
    const int w    = tid >> 6;
    const int lane = tid & 63;
    const int g    = lane >> 4;
    const int r    = lane & 15;
    const int swz  = (r & 7) << 3;   // element-XOR within a 64-elt (128B) row

    const int bh = blockIdx.y;
    const int b  = bh >> 4, h = bh & 15;

    const __hip_bfloat16* Qh = Q  + (size_t)bh * SEQL * HDIM;
    const __hip_bfloat16* Kh = K  + (size_t)bh * SEQL * HDIM;
    const __hip_bfloat16* Vh = Vt + (size_t)bh * HDIM * SEQL;

    const int sp = blockIdx.x * 4 + w;   // 0..31

#pragma unroll 1
    for (int ti = 0; ti < 2; ++ti) {
        const int strip = ti ? (63 - sp) : sp;
        const int qb = strip * 32;

        bf16x8 qf[2][2];
#pragma unroll
        for (int m = 0; m < 2; ++m)
#pragma unroll
            for (int hh = 0; hh < 2; ++hh)
                qf[m][hh] = *reinterpret_cast<const bf16x8*>(
                    Qh + (size_t)(qb + 16*m + r) * HDIM + 32*hh + 8*g);

        f32x4 o[2][4];
        float mrow[2], lrow[2];
#pragma unroll
        for (int m = 0; m < 2; ++m) {
#pragma unroll
            for (int n = 0; n < 4; ++n) o[m][n] = (f32x4)0.0f;
            mrow[m] = -1e30f; lrow[m] = 0.0f;
        }

        const int nst = ((qb + 31) >> 6) + 1;
#pragma unroll 1
        for (int kt = 0; kt < nst; ++kt) {
            const int key0 = kt * 64;

            bf16x8 kf[4][2];
#pragma unroll
            for (int c = 0; c < 4; ++c)
#pragma unroll
                for (int hh = 0; hh < 2; ++hh)
                    kf[c][hh] = *reinterpret_cast<const bf16x8*>(
                        Kh + (size_t)(key0 + 16*c + r) * HDIM + 32*hh + 8*g);

            // S^T[key = key0+16c+4g+j][qrow = qb+16m+r]
            f32x4 s[2][4];
#pragma unroll
            for (int m = 0; m < 2; ++m)
#pragma unroll
                for (int c = 0; c < 4; ++c) {
                    f32x4 t = (f32x4)0.0f;
                    t = mfma16(kf[c][0], qf[m][0], t);
                    t = mfma16(kf[c][1], qf[m][1], t);
                    s[m][c] = t;
                }

            if (kt == nst - 1) {   // causal mask only in the boundary step
#pragma unroll
                for (int m = 0; m < 2; ++m) {
                    const int qrow = qb + 16*m + r;
#pragma unroll
                    for (int c = 0; c < 4; ++c) {
                        const int kb = key0 + 16*c + 4*g;
#pragma unroll
                        for (int j = 0; j < 4; ++j)
                            if (kb + j > qrow) s[m][c][j] = -1e30f;
                    }
                }
            }

#pragma unroll
            for (int m = 0; m < 2; ++m) {
                // row-max: in-reg tree (16 vals, one q-row) + 2 cross-lane hops
                float t0 = fmaxf(fmaxf(s[m][0][0], s[m][0][1]), fmaxf(s[m][0][2], s[m][0][3]));
                float t1 = fmaxf(fmaxf(s[m][1][0], s[m][1][1]), fmaxf(s[m][1][2], s[m][1][3]));
                float t2 = fmaxf(fmaxf(s[m][2][0], s[m][2][1]), fmaxf(s[m][2][2], s[m][2][3]));
                float t3 = fmaxf(fmaxf(s[m][3][0], s[m][3][1]), fmaxf(s[m][3][2], s[m][3][3]));
                float pm = fmaxf(fmaxf(t0, t1), fmaxf(t2, t3));
                pm = fmaxf(pm, __shfl_xor(pm, 16));
                pm = fmaxf(pm, __shfl_xor(pm, 32));

                // defer-max: rescale only when max grew materially (log2 domain)
                if (__any(pm > mrow[m] + 11.0f)) {
                    const float mnew = fmaxf(mrow[m], pm);
                    const float fac  = exp2f(mrow[m] - mnew);
                    mrow[m] = mnew;
                    lrow[m] *= fac;
#pragma unroll
                    for (int n = 0; n < 4; ++n) o[m][n] *= fac;
                }

                float p[4][4];
#pragma unroll
                for (int c = 0; c < 4; ++c)
#pragma unroll
                    for (int j = 0; j < 4; ++j)
                        p[c][j] = exp2f(s[m][c][j] - mrow[m]);

                float u0 = (p[0][0] + p[0][1]) + (p[0][2] + p[0][3]);
                float u1 = (p[1][0] + p[1][1]) + (p[1][2] + p[1][3]);
                float u2 = (p[2][0] + p[2][1]) + (p[2][2] + p[2][3]);
                float u3 = (p[3][0] + p[3][1]) + (p[3][2] + p[3][3]);
                float ps = (u0 + u1) + (u2 + u3);
                ps += __shfl_xor(ps, 16);
                ps += __shfl_xor(ps, 32);
                lrow[m] += ps;

                // pack P row-fragment: 4 bf16 per c -> swizzled ds_write_b64
#pragma unroll
                for (int c = 0; c < 4; ++c) {
                    ushort4 pk4;
                    pk4.x = f2bf(p[c][0]); pk4.y = f2bf(p[c][1]);
                    pk4.z = f2bf(p[c][2]); pk4.w = f2bf(p[c][3]);
                    *reinterpret_cast<ushort4*>(&Ps[w][m][r][(16*c + 4*g) ^ swz]) = pk4;
                }
            }

            // P fragments (swizzled b128 reads) + PV as mfma(V^T, P^T)
            bf16x8 pf[2][2];
#pragma unroll
            for (int m = 0; m < 2; ++m)
#pragma unroll
                for (int hh = 0; hh < 2; ++hh)
                    pf[m][hh] = *reinterpret_cast<const bf16x8*>(
                        &Ps[w][m][r][(32*hh + 8*g) ^ swz]);

#pragma unroll
            for (int n = 0; n < 4; ++n) {
                bf16x8 vf0 = *reinterpret_cast<const bf16x8*>(
                    Vh + (size_t)(16*n + r) * SEQL + key0 + 8*g);
                bf16x8 vf1 = *reinterpret_cast<const bf16x8*>(
                    Vh + (size_t)(16*n + r) * SEQL + key0 + 32 + 8*g);
#pragma unroll
                for (int m = 0; m < 2; ++m) {
                    o[m][n] = mfma16(vf0, pf[m][0], o[m][n]);
                    o[m][n] = mfma16(vf1, pf[m][1], o[m][n]);
                }
            }
        }

        // epilogue: O^T fragment -> ctx row-major; per-lane row, 8B packed stores
#pragma unroll
        for (int m = 0; m < 2; ++m) {
            const float inv = 1.0f / lrow[m];
            const size_t rowbase = (size_t)(b*SEQL + qb + 16*m + r) * DOUT + h*HDIM;
#pragma unroll
            for (int n = 0; n < 4; ++n) {
                ushort4 ov;
                ov.x = f2bf(o[m][n][0] * inv); ov.y = f2bf(o[m][n][1] * inv);
                ov.z = f2bf(o[m][n][2] * inv); ov.w = f2bf(o[m][n][3] * inv);
                *reinterpret_cast<ushort4*>(&ctx[rowbase + 16*n + 4*g]) = ov;
            }
        }
    }
}

extern "C" void kernel_launch(void* const* d_in, const int* in_sizes, int n_in,
                              void* d_out, int out_size, void* d_ws, size_t ws_size,
                              hipStream_t stream) {
    const float* x  = (const float*)d_in[0];
    const float* Wq = (const float*)d_in[1];
    const float* bq = (const float*)d_in[2];
    const float* Wk = (const float*)d_in[3];
    const float* bk = (const float*)d_in[4];
    const float* Wv = (const float*)d_in[5];
    const float* bv = (const float*)d_in[6];
    const float* Wo = (const float*)d_in[7];
    const float* bo = (const float*)d_in[8];
    float* out = (float*)d_out;
    (void)in_sizes; (void)n_in; (void)out_size; (void)ws_size;

    char* ws = (char*)d_ws;
    __hip_bfloat16* xb  = (__hip_bfloat16*)ws;                       // 16 MB
    __hip_bfloat16* Wt3 = (__hip_bfloat16*)(ws + (16u << 20));       // 6 MB (Q,K,V slabs)
    __hip_bfloat16* Wot = (__hip_bfloat16*)(ws + (22u << 20));       // 2 MB
    __hip_bfloat16* Qb  = (__hip_bfloat16*)(ws + (24u << 20));       // 16 MB
    __hip_bfloat16* Kb  = Qb + (size_t)MTOT * DOUT;                  // 16 MB
    __hip_bfloat16* Vtb = Kb + (size_t)MTOT * DOUT;                  // 16 MB
    __hip_bfloat16* ctx = xb;  // alias: xb dead after the QKV GEMM

    cvt_bf16<<<2048, 256, 0, stream>>>((const float4*)x, (ushort4*)xb, MTOT * DIN / 4);

    dim3 tb(32, 8);
    transpose_cvt3<<<dim3(32, 32, 3), tb, 0, stream>>>(Wq, Wk, Wv, Wt3);
    transpose_cvt <<<dim3(32, 32),    tb, 0, stream>>>(Wo, Wot);

    // fused QKV GEMM, 256^2 tiles: grid (3072/256, 8192/256) = (12, 32) = 384 blocks
    dim3 gq(3*DOUT / 256, MTOT / 256);
    gemm_qkv256<<<gq, 512, 0, stream>>>(xb, Wt3, bq, bk, bv, Qb, Kb, Vtb,
                                        0.125f * 1.44269504088896f);

    dim3 ag(8, BSZ * NHEAD);  // 32 strip-pairs per bh / 4 waves = 8 blocks x 64 (b,h)
    attn_fwd<<<ag, 256, 0, stream>>>(Qb, Kb, Vtb, ctx);

    // out-proj (128^2, swapped orientation, f32x4 stores)
    dim3 gg(DOUT / 128, MTOT / 128);  // (8, 64)
    gemm_out128<<<gg, 256, 0, stream>>>(ctx, Wot, bo, out);
}

// Round 7
// 670.720 us; speedup vs baseline: 1.0021x; 1.0021x over previous
//
#include <hip/hip_runtime.h>
#include <hip/hip_bf16.h>
#include <stdint.h>

#define DIN   1024
#define DOUT  1024
#define NHEAD 16
#define HDIM  64
#define SEQL  2048
#define BSZ   4
#define MTOT  (BSZ*SEQL)   // 8192
#define KDIM  1024

typedef __bf16 bf16x8 __attribute__((ext_vector_type(8)));
typedef float  f32x4  __attribute__((ext_vector_type(4)));

__device__ __forceinline__ f32x4 mfma16(bf16x8 a, bf16x8 b, f32x4 c) {
    return __builtin_amdgcn_mfma_f32_16x16x32_bf16(a, b, c, 0, 0, 0);
}

__device__ __forceinline__ void gl_lds16(const void* gsrc, void* ldst) {
    __builtin_amdgcn_global_load_lds(
        (const __attribute__((address_space(1))) uint32_t*)gsrc,
        (__attribute__((address_space(3))) uint32_t*)ldst, 16, 0, 0);
}

__device__ __forceinline__ unsigned short f2bf(float f) {
    union { __hip_bfloat16 h; unsigned short u; } cv;
    cv.h = __float2bfloat16(f);
    return cv.u;
}

// ---------------- fp32 -> bf16 elementwise (vectorized) ----------------
__global__ void cvt_bf16(const float4* __restrict__ in, ushort4* __restrict__ out, int n4) {
    int idx = blockIdx.x * blockDim.x + threadIdx.x;
    int stride = gridDim.x * blockDim.x;
    for (int i = idx; i < n4; i += stride) {
        float4 v = in[i];
        ushort4 o;
        o.x = f2bf(v.x); o.y = f2bf(v.y); o.z = f2bf(v.z); o.w = f2bf(v.w);
        out[i] = o;
    }
}

// ---- transpose + convert 3x W[1024][1024] f32 -> one Wt3[3072][1024] bf16 ----
__global__ void transpose_cvt3(const float* __restrict__ W0, const float* __restrict__ W1,
                               const float* __restrict__ W2, __hip_bfloat16* __restrict__ Wt3) {
    __shared__ __hip_bfloat16 t[32][33];
    const int tx = threadIdx.x, ty = threadIdx.y;   // (32, 8)
    const int bx = blockIdx.x, by = blockIdx.y, z = blockIdx.z;
    const float* W = (z == 0) ? W0 : (z == 1) ? W1 : W2;
    __hip_bfloat16* Wt = Wt3 + (size_t)z * DOUT * DIN;
#pragma unroll
    for (int r = 0; r < 4; ++r)
        t[ty + 8*r][tx] = __float2bfloat16(W[(size_t)(by*32 + ty + 8*r) * DOUT + bx*32 + tx]);
    __syncthreads();
#pragma unroll
    for (int r = 0; r < 4; ++r)
        Wt[(size_t)(bx*32 + ty + 8*r) * DIN + by*32 + tx] = t[tx][ty + 8*r];
}

__global__ void transpose_cvt(const float* __restrict__ W, __hip_bfloat16* __restrict__ Wt) {
    __shared__ __hip_bfloat16 t[32][33];
    const int tx = threadIdx.x, ty = threadIdx.y;
    const int bx = blockIdx.x, by = blockIdx.y;
#pragma unroll
    for (int r = 0; r < 4; ++r)
        t[ty + 8*r][tx] = __float2bfloat16(W[(size_t)(by*32 + ty + 8*r) * DOUT + bx*32 + tx]);
    __syncthreads();
#pragma unroll
    for (int r = 0; r < 4; ++r)
        Wt[(size_t)(bx*32 + ty + 8*r) * DIN + by*32 + tx] = t[tx][ty + 8*r];
}

// ---------------- fused QKV GEMM: 256x256 tile, 8 waves, BK=32, 2-phase ----------------
// C = x[8192,1024] * Wt3[3072,1024]^T.  N-slabs: [0,1024)=Q (swapped mfma -> C^T,
// packed d-stores, *scale), [1024,2048)=K (same, no scale), [2048,3072)=V (normal
// mfma, packed seq-stores into V^T [B,H,64,S]).
// REGISTER BUDGET: acc[8][4]=128 f32 + ~70 frag/addr => need ~200 VGPR.
// R5/R6 showed both __launch_bounds__(512,2) and (512) cap at 128 VGPR (backend
// budgets 4 waves/EU) -> accumulator spill, 1.1 GB scratch writes. Pin the
// budget explicitly: amdgpu_waves_per_eu(2) -> cap 512/2 = 256 VGPR.
__global__ __attribute__((amdgpu_waves_per_eu(2))) __launch_bounds__(512)
void gemm_qkv256(const __hip_bfloat16* __restrict__ A,
                 const __hip_bfloat16* __restrict__ Bt,
                 const float* __restrict__ bq, const float* __restrict__ bk,
                 const float* __restrict__ bv,
                 __hip_bfloat16* __restrict__ Qo, __hip_bfloat16* __restrict__ Ko,
                 __hip_bfloat16* __restrict__ Vo,
                 float qscale)
{
    __shared__ alignas(16) __hip_bfloat16 As[2][4][256][8];   // 32 KB
    __shared__ alignas(16) __hip_bfloat16 Bs[2][4][256][8];   // 32 KB

    const int tid  = threadIdx.x;
    const int w    = tid >> 6;        // 0..7
    const int lane = tid & 63;
    const int g    = lane >> 4;
    const int r    = lane & 15;
    const int wr   = w >> 2;          // 0..1 (M half)
    const int wc   = w & 3;           // 0..3 (N quarter)
    const int sg   = w & 3;           // staging k-group
    const int sb   = w >> 2;          // staging row-half

    const int row0 = blockIdx.y * 256;
    const int col0 = blockIdx.x * 256;
    const bool vslab = (col0 >= 2048);

    f32x4 acc[8][4];
#pragma unroll
    for (int m = 0; m < 8; ++m)
#pragma unroll
        for (int n = 0; n < 4; ++n) acc[m][n] = (f32x4)0.0f;

    auto stage = [&](int buf, int kt) {
        const __hip_bfloat16* ga = A  + (size_t)(row0 + sb*128 + lane) * KDIM + kt*32 + 8*sg;
        const __hip_bfloat16* gb = Bt + (size_t)(col0 + sb*128 + lane) * KDIM + kt*32 + 8*sg;
        gl_lds16(ga,           &As[buf][sg][sb*128     ][0]);
        gl_lds16(ga + 64*KDIM, &As[buf][sg][sb*128 + 64][0]);
        gl_lds16(gb,           &Bs[buf][sg][sb*128     ][0]);
        gl_lds16(gb + 64*KDIM, &Bs[buf][sg][sb*128 + 64][0]);
    };

    stage(0, 0);
    __syncthreads();

    const int NKT = KDIM / 32;
    for (int kt = 0; kt < NKT; ++kt) {
        const int cur = kt & 1;
        if (kt + 1 < NKT) stage(cur ^ 1, kt + 1);

        bf16x8 af[8], bfr[4];
#pragma unroll
        for (int m = 0; m < 8; ++m)
            af[m] = *reinterpret_cast<const bf16x8*>(&As[cur][g][wr*128 + 16*m + r][0]);
#pragma unroll
        for (int n = 0; n < 4; ++n)
            bfr[n] = *reinterpret_cast<const bf16x8*>(&Bs[cur][g][wc*64 + 16*n + r][0]);

        if (!vslab) {
#pragma unroll
            for (int m = 0; m < 8; ++m)
#pragma unroll
                for (int n = 0; n < 4; ++n)
                    acc[m][n] = mfma16(bfr[n], af[m], acc[m][n]);   // C^T
        } else {
#pragma unroll
            for (int m = 0; m < 8; ++m)
#pragma unroll
                for (int n = 0; n < 4; ++n)
                    acc[m][n] = mfma16(af[m], bfr[n], acc[m][n]);   // C
        }

        __syncthreads();
    }

    if (!vslab) {
        // C^T frag: lane row (r) = seq row; regs j = 4 consecutive d-cols
        const int slab = col0 >> 10;            // 0=Q, 1=K (block-uniform)
        const float* bp = (slab == 0) ? bq : bk;
        __hip_bfloat16* op = (slab == 0) ? Qo : Ko;
        const float sc = (slab == 0) ? qscale : 1.0f;
#pragma unroll
        for (int m = 0; m < 8; ++m) {
            const int rowg = row0 + wr*128 + 16*m + r;
            const int bb = rowg >> 11, sq = rowg & (SEQL-1);
#pragma unroll
            for (int n = 0; n < 4; ++n) {
                const int c2 = (col0 & 1023) + wc*64 + 16*n + 4*g;
                const int hh = c2 >> 6, dd = c2 & (HDIM-1);
                const float4 bv4 = *reinterpret_cast<const float4*>(&bp[c2]);
                ushort4 ov;
                ov.x = f2bf((acc[m][n][0] + bv4.x) * sc);
                ov.y = f2bf((acc[m][n][1] + bv4.y) * sc);
                ov.z = f2bf((acc[m][n][2] + bv4.z) * sc);
                ov.w = f2bf((acc[m][n][3] + bv4.w) * sc);
                *reinterpret_cast<ushort4*>(
                    &op[(((size_t)(bb*NHEAD + hh) * SEQL + sq) << 6) + dd]) = ov;
            }
        }
    } else {
        // C frag: lane col (r) = d; regs j = 4 consecutive seq rows -> V^T contiguous
#pragma unroll
        for (int n = 0; n < 4; ++n) {
            const int colg = (col0 - 2048) + wc*64 + 16*n + r;
            const int hh = colg >> 6, dd = colg & (HDIM-1);
            const float bvv = bv[colg];
#pragma unroll
            for (int m = 0; m < 8; ++m) {
                const int rowg0 = row0 + wr*128 + 16*m + 4*g;
                const int bb = rowg0 >> 11, sq0 = rowg0 & (SEQL-1);
                ushort4 ov;
                ov.x = f2bf(acc[m][n][0] + bvv);
                ov.y = f2bf(acc[m][n][1] + bvv);
                ov.z = f2bf(acc[m][n][2] + bvv);
                ov.w = f2bf(acc[m][n][3] + bvv);
                *reinterpret_cast<ushort4*>(
                    &Vo[((size_t)(bb*NHEAD + hh) * HDIM + dd) * SEQL + sq0]) = ov;
            }
        }
    }
}

// ---------------- out-proj GEMM: 128x128 tile, swapped mfma, f32x4 stores ----------------
__global__ __launch_bounds__(256)
void gemm_out128(const __hip_bfloat16* __restrict__ A,
                 const __hip_bfloat16* __restrict__ Bt,
                 const float* __restrict__ b0,
                 float* __restrict__ o0)
{
    __shared__ alignas(16) __hip_bfloat16 As[2][4][128][8];
    __shared__ alignas(16) __hip_bfloat16 Bs[2][4][128][8];

    const int tid  = threadIdx.x;
    const int w    = tid >> 6;
    const int lane = tid & 63;
    const int g    = lane >> 4;
    const int r    = lane & 15;
    const int wr   = w >> 1, wc = w & 1;

    const int row0 = blockIdx.y * 128;
    const int col0 = blockIdx.x * 128;

    f32x4 acc[4][4];
#pragma unroll
    for (int m = 0; m < 4; ++m)
#pragma unroll
        for (int n = 0; n < 4; ++n) acc[m][n] = (f32x4)0.0f;

    auto stage = [&](int buf, int kt) {
        const __hip_bfloat16* ga = A  + (size_t)(row0 + lane) * KDIM + kt*32 + 8*w;
        const __hip_bfloat16* gb = Bt + (size_t)(col0 + lane) * KDIM + kt*32 + 8*w;
        gl_lds16(ga,            &As[buf][w][0][0]);
        gl_lds16(ga + 64*KDIM,  &As[buf][w][64][0]);
        gl_lds16(gb,            &Bs[buf][w][0][0]);
        gl_lds16(gb + 64*KDIM,  &Bs[buf][w][64][0]);
    };

    stage(0, 0);
    __syncthreads();

    const int NKT = KDIM / 32;
    for (int kt = 0; kt < NKT; ++kt) {
        const int cur = kt & 1;
        if (kt + 1 < NKT) stage(cur ^ 1, kt + 1);

        bf16x8 af[4], bfr[4];
#pragma unroll
        for (int m = 0; m < 4; ++m)
            af[m] = *reinterpret_cast<const bf16x8*>(&As[cur][g][64*wr + 16*m + r][0]);
#pragma unroll
        for (int n = 0; n < 4; ++n)
            bfr[n] = *reinterpret_cast<const bf16x8*>(&Bs[cur][g][64*wc + 16*n + r][0]);

#pragma unroll
        for (int m = 0; m < 4; ++m)
#pragma unroll
            for (int n = 0; n < 4; ++n)
                acc[m][n] = mfma16(bfr[n], af[m], acc[m][n]);   // C^T

        __syncthreads();
    }

#pragma unroll
    for (int m = 0; m < 4; ++m) {
        const int rowg = row0 + 64*wr + 16*m + r;
#pragma unroll
        for (int n = 0; n < 4; ++n) {
            const int colg0 = col0 + 64*wc + 16*n + 4*g;
            const float4 bv4 = *reinterpret_cast<const float4*>(&b0[colg0]);
            float4 ov;
            ov.x = acc[m][n][0] + bv4.x;
            ov.y = acc[m][n][1] + bv4.y;
            ov.z = acc[m][n][2] + bv4.z;
            ov.w = acc[m][n][3] + bv4.w;
            *reinterpret_cast<float4*>(&o0[(size_t)rowg * DOUT + colg0]) = ov;
        }
    }
}

// ---------------- causal flash attention (swapped-operand, 32 rows/wave) ----------------
// Q,K: [B,H,S,64] bf16 (Q pre-scaled by log2e/8).  Vt: [B,H,64,S] bf16.
// ctx out: [B,S,H*64] bf16.
// 4 waves/block; each wave owns 32-row strip pair (sp, 63-sp) for causal balance.
__global__ __launch_bounds__(256)
void attn_fwd(const __hip_bfloat16* __restrict__ Q,
              const __hip_bfloat16* __restrict__ K,
              const __hip_bfloat16* __restrict__ Vt,
              __hip_bfloat16* __restrict__ ctx)
{
    __shared__ alignas(16) __hip_bfloat16 Ps[4][2][16][64];

    const int tid  = threadIdx.x;
    const int w    = tid >> 6;
    const int lane = tid & 63;
    const int g    = lane >> 4;
    const int r    = lane & 15;
    const int swz  = (r & 7) << 3;   // element-XOR within a 64-elt (128B) row

    const int bh = blockIdx.y;
    const int b  = bh >> 4, h = bh & 15;

    const __hip_bfloat16* Qh = Q  + (size_t)bh * SEQL * HDIM;
    const __hip_bfloat16* Kh = K  + (size_t)bh * SEQL * HDIM;
    const __hip_bfloat16* Vh = Vt + (size_t)bh * HDIM * SEQL;

    const int sp = blockIdx.x * 4 + w;   // 0..31

#pragma unroll 1
    for (int ti = 0; ti < 2; ++ti) {
        const int strip = ti ? (63 - sp) : sp;
        const int qb = strip * 32;

        bf16x8 qf[2][2];
#pragma unroll
        for (int m = 0; m < 2; ++m)
#pragma unroll
            for (int hh = 0; hh < 2; ++hh)
                qf[m][hh] = *reinterpret_cast<const bf16x8*>(
                    Qh + (size_t)(qb + 16*m + r) * HDIM + 32*hh + 8*g);

        f32x4 o[2][4];
        float mrow[2], lrow[2];
#pragma unroll
        for (int m = 0; m < 2; ++m) {
#pragma unroll
            for (int n = 0; n < 4; ++n) o[m][n] = (f32x4)0.0f;
            mrow[m] = -1e30f; lrow[m] = 0.0f;
        }

        const int nst = ((qb + 31) >> 6) + 1;
#pragma unroll 1
        for (int kt = 0; kt < nst; ++kt) {
            const int key0 = kt * 64;

            bf16x8 kf[4][2];
#pragma unroll
            for (int c = 0; c < 4; ++c)
#pragma unroll
                for (int hh = 0; hh < 2; ++hh)
                    kf[c][hh] = *reinterpret_cast<const bf16x8*>(
                        Kh + (size_t)(key0 + 16*c + r) * HDIM + 32*hh + 8*g);

            // S^T[key = key0+16c+4g+j][qrow = qb+16m+r]
            f32x4 s[2][4];
#pragma unroll
            for (int m = 0; m < 2; ++m)
#pragma unroll
                for (int c = 0; c < 4; ++c) {
                    f32x4 t = (f32x4)0.0f;
                    t = mfma16(kf[c][0], qf[m][0], t);
                    t = mfma16(kf[c][1], qf[m][1], t);
                    s[m][c] = t;
                }

            if (kt == nst - 1) {   // causal mask only in the boundary step
#pragma unroll
                for (int m = 0; m < 2; ++m) {
                    const int qrow = qb + 16*m + r;
#pragma unroll
                    for (int c = 0; c < 4; ++c) {
                        const int kb = key0 + 16*c + 4*g;
#pragma unroll
                        for (int j = 0; j < 4; ++j)
                            if (kb + j > qrow) s[m][c][j] = -1e30f;
                    }
                }
            }

#pragma unroll
            for (int m = 0; m < 2; ++m) {
                // row-max: in-reg tree (16 vals, one q-row) + 2 cross-lane hops
                float t0 = fmaxf(fmaxf(s[m][0][0], s[m][0][1]), fmaxf(s[m][0][2], s[m][0][3]));
                float t1 = fmaxf(fmaxf(s[m][1][0], s[m][1][1]), fmaxf(s[m][1][2], s[m][1][3]));
                float t2 = fmaxf(fmaxf(s[m][2][0], s[m][2][1]), fmaxf(s[m][2][2], s[m][2][3]));
                float t3 = fmaxf(fmaxf(s[m][3][0], s[m][3][1]), fmaxf(s[m][3][2], s[m][3][3]));
                float pm = fmaxf(fmaxf(t0, t1), fmaxf(t2, t3));
                pm = fmaxf(pm, __shfl_xor(pm, 16));
                pm = fmaxf(pm, __shfl_xor(pm, 32));

                // defer-max: rescale only when max grew materially (log2 domain)
                if (__any(pm > mrow[m] + 11.0f)) {
                    const float mnew = fmaxf(mrow[m], pm);
                    const float fac  = exp2f(mrow[m] - mnew);
                    mrow[m] = mnew;
                    lrow[m] *= fac;
#pragma unroll
                    for (int n = 0; n < 4; ++n) o[m][n] *= fac;
                }

                float p[4][4];
#pragma unroll
                for (int c = 0; c < 4; ++c)
#pragma unroll
                    for (int j = 0; j < 4; ++j)
                        p[c][j] = exp2f(s[m][c][j] - mrow[m]);

                float u0 = (p[0][0] + p[0][1]) + (p[0][2] + p[0][3]);
                float u1 = (p[1][0] + p[1][1]) + (p[1][2] + p[1][3]);
                float u2 = (p[2][0] + p[2][1]) + (p[2][2] + p[2][3]);
                float u3 = (p[3][0] + p[3][1]) + (p[3][2] + p[3][3]);
                float ps = (u0 + u1) + (u2 + u3);
                ps += __shfl_xor(ps, 16);
                ps += __shfl_xor(ps, 32);
                lrow[m] += ps;

                // pack P row-fragment: 4 bf16 per c -> swizzled ds_write_b64
#pragma unroll
                for (int c = 0; c < 4; ++c) {
                    ushort4 pk4;
                    pk4.x = f2bf(p[c][0]); pk4.y = f2bf(p[c][1]);
                    pk4.z = f2bf(p[c][2]); pk4.w = f2bf(p[c][3]);
                    *reinterpret_cast<ushort4*>(&Ps[w][m][r][(16*c + 4*g) ^ swz]) = pk4;
                }
            }

            // P fragments (swizzled b128 reads) + PV as mfma(V^T, P^T)
            bf16x8 pf[2][2];
#pragma unroll
            for (int m = 0; m < 2; ++m)
#pragma unroll
                for (int hh = 0; hh < 2; ++hh)
                    pf[m][hh] = *reinterpret_cast<const bf16x8*>(
                        &Ps[w][m][r][(32*hh + 8*g) ^ swz]);

#pragma unroll
            for (int n = 0; n < 4; ++n) {
                bf16x8 vf0 = *reinterpret_cast<const bf16x8*>(
                    Vh + (size_t)(16*n + r) * SEQL + key0 + 8*g);
                bf16x8 vf1 = *reinterpret_cast<const bf16x8*>(
                    Vh + (size_t)(16*n + r) * SEQL + key0 + 32 + 8*g);
#pragma unroll
                for (int m = 0; m < 2; ++m) {
                    o[m][n] = mfma16(vf0, pf[m][0], o[m][n]);
                    o[m][n] = mfma16(vf1, pf[m][1], o[m][n]);
                }
            }
        }

        // epilogue: O^T fragment -> ctx row-major; per-lane row, 8B packed stores
#pragma unroll
        for (int m = 0; m < 2; ++m) {
            const float inv = 1.0f / lrow[m];
            const size_t rowbase = (size_t)(b*SEQL + qb + 16*m + r) * DOUT + h*HDIM;
#pragma unroll
            for (int n = 0; n < 4; ++n) {
                ushort4 ov;
                ov.x = f2bf(o[m][n][0] * inv); ov.y = f2bf(o[m][n][1] * inv);
                ov.z = f2bf(o[m][n][2] * inv); ov.w = f2bf(o[m][n][3] * inv);
                *reinterpret_cast<ushort4*>(&ctx[rowbase + 16*n + 4*g]) = ov;
            }
        }
    }
}

extern "C" void kernel_launch(void* const* d_in, const int* in_sizes, int n_in,
                              void* d_out, int out_size, void* d_ws, size_t ws_size,
                              hipStream_t stream) {
    const float* x  = (const float*)d_in[0];
    const float* Wq = (const float*)d_in[1];
    const float* bq = (const float*)d_in[2];
    const float* Wk = (const float*)d_in[3];
    const float* bk = (const float*)d_in[4];
    const float* Wv = (const float*)d_in[5];
    const float* bv = (const float*)d_in[6];
    const float* Wo = (const float*)d_in[7];
    const float* bo = (const float*)d_in[8];
    float* out = (float*)d_out;
    (void)in_sizes; (void)n_in; (void)out_size; (void)ws_size;

    char* ws = (char*)d_ws;
    __hip_bfloat16* xb  = (__hip_bfloat16*)ws;                       // 16 MB
    __hip_bfloat16* Wt3 = (__hip_bfloat16*)(ws + (16u << 20));       // 6 MB (Q,K,V slabs)
    __hip_bfloat16* Wot = (__hip_bfloat16*)(ws + (22u << 20));       // 2 MB
    __hip_bfloat16* Qb  = (__hip_bfloat16*)(ws + (24u << 20));       // 16 MB
    __hip_bfloat16* Kb  = Qb + (size_t)MTOT * DOUT;                  // 16 MB
    __hip_bfloat16* Vtb = Kb + (size_t)MTOT * DOUT;                  // 16 MB
    __hip_bfloat16* ctx = xb;  // alias: xb dead after the QKV GEMM

    cvt_bf16<<<2048, 256, 0, stream>>>((const float4*)x, (ushort4*)xb, MTOT * DIN / 4);

    dim3 tb(32, 8);
    transpose_cvt3<<<dim3(32, 32, 3), tb, 0, stream>>>(Wq, Wk, Wv, Wt3);
    transpose_cvt <<<dim3(32, 32),    tb, 0, stream>>>(Wo, Wot);

    // fused QKV GEMM, 256^2 tiles: grid (3072/256, 8192/256) = (12, 32) = 384 blocks
    dim3 gq(3*DOUT / 256, MTOT / 256);
    gemm_qkv256<<<gq, 512, 0, stream>>>(xb, Wt3, bq, bk, bv, Qb, Kb, Vtb,
                                        0.125f * 1.44269504088896f);

    dim3 ag(8, BSZ * NHEAD);  // 32 strip-pairs per bh / 4 waves = 8 blocks x 64 (b,h)
    attn_fwd<<<ag, 256, 0, stream>>>(Qb, Kb, Vtb, ctx);

    // out-proj (128^2, swapped orientation, f32x4 stores)
    dim3 gg(DOUT / 128, MTOT / 128);  // (8, 64)
    gemm_out128<<<gg, 256, 0, stream>>>(ctx, Wot, bo, out);
}

// Round 8
// 412.326 us; speedup vs baseline: 1.6301x; 1.6267x over previous
//
#include <hip/hip_runtime.h>
#include <hip/hip_bf16.h>
#include <stdint.h>

#define DIN   1024
#define DOUT  1024
#define NHEAD 16
#define HDIM  64
#define SEQL  2048
#define BSZ   4
#define MTOT  (BSZ*SEQL)   // 8192
#define KDIM  1024

typedef __bf16 bf16x8 __attribute__((ext_vector_type(8)));
typedef float  f32x4  __attribute__((ext_vector_type(4)));

__device__ __forceinline__ f32x4 mfma16(bf16x8 a, bf16x8 b, f32x4 c) {
    return __builtin_amdgcn_mfma_f32_16x16x32_bf16(a, b, c, 0, 0, 0);
}

__device__ __forceinline__ void gl_lds16(const void* gsrc, void* ldst) {
    __builtin_amdgcn_global_load_lds(
        (const __attribute__((address_space(1))) uint32_t*)gsrc,
        (__attribute__((address_space(3))) uint32_t*)ldst, 16, 0, 0);
}

__device__ __forceinline__ unsigned short f2bf(float f) {
    union { __hip_bfloat16 h; unsigned short u; } cv;
    cv.h = __float2bfloat16(f);
    return cv.u;
}

// ---------------- fp32 -> bf16 elementwise (vectorized) ----------------
__global__ void cvt_bf16(const float4* __restrict__ in, ushort4* __restrict__ out, int n4) {
    int idx = blockIdx.x * blockDim.x + threadIdx.x;
    int stride = gridDim.x * blockDim.x;
    for (int i = idx; i < n4; i += stride) {
        float4 v = in[i];
        ushort4 o;
        o.x = f2bf(v.x); o.y = f2bf(v.y); o.z = f2bf(v.z); o.w = f2bf(v.w);
        out[i] = o;
    }
}

// ---- transpose + convert 3x W[1024][1024] f32 -> one Wt3[3072][1024] bf16 ----
__global__ void transpose_cvt3(const float* __restrict__ W0, const float* __restrict__ W1,
                               const float* __restrict__ W2, __hip_bfloat16* __restrict__ Wt3) {
    __shared__ __hip_bfloat16 t[32][33];
    const int tx = threadIdx.x, ty = threadIdx.y;   // (32, 8)
    const int bx = blockIdx.x, by = blockIdx.y, z = blockIdx.z;
    const float* W = (z == 0) ? W0 : (z == 1) ? W1 : W2;
    __hip_bfloat16* Wt = Wt3 + (size_t)z * DOUT * DIN;
#pragma unroll
    for (int r = 0; r < 4; ++r)
        t[ty + 8*r][tx] = __float2bfloat16(W[(size_t)(by*32 + ty + 8*r) * DOUT + bx*32 + tx]);
    __syncthreads();
#pragma unroll
    for (int r = 0; r < 4; ++r)
        Wt[(size_t)(bx*32 + ty + 8*r) * DIN + by*32 + tx] = t[tx][ty + 8*r];
}

__global__ void transpose_cvt(const float* __restrict__ W, __hip_bfloat16* __restrict__ Wt) {
    __shared__ __hip_bfloat16 t[32][33];
    const int tx = threadIdx.x, ty = threadIdx.y;
    const int bx = blockIdx.x, by = blockIdx.y;
#pragma unroll
    for (int r = 0; r < 4; ++r)
        t[ty + 8*r][tx] = __float2bfloat16(W[(size_t)(by*32 + ty + 8*r) * DOUT + bx*32 + tx]);
    __syncthreads();
#pragma unroll
    for (int r = 0; r < 4; ++r)
        Wt[(size_t)(bx*32 + ty + 8*r) * DIN + by*32 + tx] = t[tx][ty + 8*r];
}

// ---------------- 128x128-tile MFMA GEMM (256 threads, 4 waves, BK=32) ----------------
// EPI 0 (QK, swapped mfma -> C^T fragments, packed 8B stores):
//   N=2048, slab0 -> Q head-major *scale, slab1 -> K head-major. biases b0,b1.
// EPI 1 (V, normal mfma, 4 consecutive seq rows per lane -> packed 8B stores):
//   N=1024 -> V^T [B,H,64,S]. bias b0.
// EPI 2 (out-proj, swapped mfma, packed 16B f32 stores): N=1024 f32 row-major.
// NOTE: 256-thread blocks only. 512-thread blocks get a 128-VGPR budget on this
// toolchain (R5-R7: launch_bounds/waves_per_eu attempts all ignored) -> acc spill.
template <int EPI>
__global__ __launch_bounds__(256)
void gemm_mfma(const __hip_bfloat16* __restrict__ A,
               const __hip_bfloat16* __restrict__ Bt,
               const float* __restrict__ b0, const float* __restrict__ b1,
               void* __restrict__ o0, void* __restrict__ o1,
               float scale)
{
    __shared__ alignas(16) __hip_bfloat16 As[2][4][128][8];
    __shared__ alignas(16) __hip_bfloat16 Bs[2][4][128][8];

    const int tid  = threadIdx.x;
    const int w    = tid >> 6;
    const int lane = tid & 63;
    const int g    = lane >> 4;
    const int r    = lane & 15;
    const int wr   = w >> 1, wc = w & 1;

    const int row0 = blockIdx.y * 128;
    const int col0 = blockIdx.x * 128;

    f32x4 acc[4][4];
#pragma unroll
    for (int m = 0; m < 4; ++m)
#pragma unroll
        for (int n = 0; n < 4; ++n) acc[m][n] = (f32x4)0.0f;

    auto stage = [&](int buf, int kt) {
        const __hip_bfloat16* ga = A  + (size_t)(row0 + lane) * KDIM + kt*32 + 8*w;
        const __hip_bfloat16* gb = Bt + (size_t)(col0 + lane) * KDIM + kt*32 + 8*w;
        gl_lds16(ga,            &As[buf][w][0][0]);
        gl_lds16(ga + 64*KDIM,  &As[buf][w][64][0]);
        gl_lds16(gb,            &Bs[buf][w][0][0]);
        gl_lds16(gb + 64*KDIM,  &Bs[buf][w][64][0]);
    };

    stage(0, 0);
    __syncthreads();

    const int NKT = KDIM / 32;
    for (int kt = 0; kt < NKT; ++kt) {
        const int cur = kt & 1;
        if (kt + 1 < NKT) stage(cur ^ 1, kt + 1);

        bf16x8 af[4], bfr[4];
#pragma unroll
        for (int m = 0; m < 4; ++m)
            af[m] = *reinterpret_cast<const bf16x8*>(&As[cur][g][64*wr + 16*m + r][0]);
#pragma unroll
        for (int n = 0; n < 4; ++n)
            bfr[n] = *reinterpret_cast<const bf16x8*>(&Bs[cur][g][64*wc + 16*n + r][0]);

#pragma unroll
        for (int m = 0; m < 4; ++m)
#pragma unroll
            for (int n = 0; n < 4; ++n) {
                if (EPI == 1) acc[m][n] = mfma16(af[m], bfr[n], acc[m][n]);  // C
                else          acc[m][n] = mfma16(bfr[n], af[m], acc[m][n]);  // C^T
            }

        __syncthreads();
    }

    if (EPI == 0) {
        // C^T frag: lane row = rowg (seq), regs j = 4 consecutive cols (d within head)
        const int slab = col0 >> 10;                    // block-uniform
        const float* bp = (slab == 0) ? b0 : b1;
        __hip_bfloat16* op = (__hip_bfloat16*)((slab == 0) ? o0 : o1);
        const float sc = (slab == 0) ? scale : 1.0f;
#pragma unroll
        for (int m = 0; m < 4; ++m) {
            const int rowg = row0 + 64*wr + 16*m + r;
            const int bb = rowg >> 11, sq = rowg & (SEQL-1);
#pragma unroll
            for (int n = 0; n < 4; ++n) {
                const int c2 = (col0 & 1023) + 64*wc + 16*n + 4*g;
                const int hh = c2 >> 6, dd = c2 & (HDIM-1);
                const float4 bv4 = *reinterpret_cast<const float4*>(&bp[c2]);
                ushort4 ov;
                ov.x = f2bf((acc[m][n][0] + bv4.x) * sc);
                ov.y = f2bf((acc[m][n][1] + bv4.y) * sc);
                ov.z = f2bf((acc[m][n][2] + bv4.z) * sc);
                ov.w = f2bf((acc[m][n][3] + bv4.w) * sc);
                *reinterpret_cast<ushort4*>(
                    &op[(((size_t)(bb*NHEAD + hh) * SEQL + sq) << 6) + dd]) = ov;
            }
        }
    } else if (EPI == 1) {
        // C frag: lane col = colg (d), regs j = 4 consecutive seq rows -> V^T contiguous
#pragma unroll
        for (int n = 0; n < 4; ++n) {
            const int colg = col0 + 64*wc + 16*n + r;
            const int hh = colg >> 6, dd = colg & (HDIM-1);
            const float bv_ = b0[colg];
#pragma unroll
            for (int m = 0; m < 4; ++m) {
                const int rowg0 = row0 + 64*wr + 16*m + 4*g;
                const int bb = rowg0 >> 11, sq0 = rowg0 & (SEQL-1);
                ushort4 ov;
                ov.x = f2bf(acc[m][n][0] + bv_);
                ov.y = f2bf(acc[m][n][1] + bv_);
                ov.z = f2bf(acc[m][n][2] + bv_);
                ov.w = f2bf(acc[m][n][3] + bv_);
                *reinterpret_cast<ushort4*>(
                    &((__hip_bfloat16*)o0)[((size_t)(bb*NHEAD + hh) * HDIM + dd) * SEQL + sq0]) = ov;
            }
        }
    } else {
        // C^T frag -> f32 row-major, 16B stores
#pragma unroll
        for (int m = 0; m < 4; ++m) {
            const int rowg = row0 + 64*wr + 16*m + r;
#pragma unroll
            for (int n = 0; n < 4; ++n) {
                const int colg0 = col0 + 64*wc + 16*n + 4*g;
                const float4 bv4 = *reinterpret_cast<const float4*>(&b0[colg0]);
                float4 ov;
                ov.x = acc[m][n][0] + bv4.x;
                ov.y = acc[m][n][1] + bv4.y;
                ov.z = acc[m][n][2] + bv4.z;
                ov.w = acc[m][n][3] + bv4.w;
                *reinterpret_cast<float4*>(&((float*)o0)[(size_t)rowg * DOUT + colg0]) = ov;
            }
        }
    }
}

// ---------------- causal flash attention (swapped-operand, 32 rows/wave) ----------------
// Q,K: [B,H,S,64] bf16 (Q pre-scaled by log2e/8).  Vt: [B,H,64,S] bf16.
// ctx out: [B,S,H*64] bf16.
// 4 waves/block, ONE 32-row strip per wave; grid (16, 64) = 1024 blocks ->
// 4 blocks/CU = 16 waves/CU (R3 had 8). Longest strips dispatch first
// (strip = 63 - gsp) so short blocks backfill the causal tail.
__global__ __launch_bounds__(256)
void attn_fwd(const __hip_bfloat16* __restrict__ Q,
              const __hip_bfloat16* __restrict__ K,
              const __hip_bfloat16* __restrict__ Vt,
              __hip_bfloat16* __restrict__ ctx)
{
    __shared__ alignas(16) __hip_bfloat16 Ps[4][2][16][64];

    const int tid  = threadIdx.x;
    const int w    = tid >> 6;
    const int lane = tid & 63;
    const int g    = lane >> 4;
    const int r    = lane & 15;
    const int swz  = (r & 7) << 3;   // element-XOR within a 64-elt (128B) row

    const int bh = blockIdx.y;
    const int b  = bh >> 4, h = bh & 15;

    const __hip_bfloat16* Qh = Q  + (size_t)bh * SEQL * HDIM;
    const __hip_bfloat16* Kh = K  + (size_t)bh * SEQL * HDIM;
    const __hip_bfloat16* Vh = Vt + (size_t)bh * HDIM * SEQL;

    const int gsp   = blockIdx.x * 4 + w;   // 0..63
    const int strip = 63 - gsp;             // longest first
    const int qb    = strip * 32;

    bf16x8 qf[2][2];
#pragma unroll
    for (int m = 0; m < 2; ++m)
#pragma unroll
        for (int hh = 0; hh < 2; ++hh)
            qf[m][hh] = *reinterpret_cast<const bf16x8*>(
                Qh + (size_t)(qb + 16*m + r) * HDIM + 32*hh + 8*g);

    f32x4 o[2][4];
    float mrow[2], lrow[2];
#pragma unroll
    for (int m = 0; m < 2; ++m) {
#pragma unroll
        for (int n = 0; n < 4; ++n) o[m][n] = (f32x4)0.0f;
        mrow[m] = -1e30f; lrow[m] = 0.0f;
    }

    const int nst = ((qb + 31) >> 6) + 1;
#pragma unroll 1
    for (int kt = 0; kt < nst; ++kt) {
        const int key0 = kt * 64;

        bf16x8 kf[4][2];
#pragma unroll
        for (int c = 0; c < 4; ++c)
#pragma unroll
            for (int hh = 0; hh < 2; ++hh)
                kf[c][hh] = *reinterpret_cast<const bf16x8*>(
                    Kh + (size_t)(key0 + 16*c + r) * HDIM + 32*hh + 8*g);

        // S^T[key = key0+16c+4g+j][qrow = qb+16m+r]
        f32x4 s[2][4];
#pragma unroll
        for (int m = 0; m < 2; ++m)
#pragma unroll
            for (int c = 0; c < 4; ++c) {
                f32x4 t = (f32x4)0.0f;
                t = mfma16(kf[c][0], qf[m][0], t);
                t = mfma16(kf[c][1], qf[m][1], t);
                s[m][c] = t;
            }

        if (kt == nst - 1) {   // causal mask only in the boundary step
#pragma unroll
            for (int m = 0; m < 2; ++m) {
                const int qrow = qb + 16*m + r;
#pragma unroll
                for (int c = 0; c < 4; ++c) {
                    const int kb = key0 + 16*c + 4*g;
#pragma unroll
                    for (int j = 0; j < 4; ++j)
                        if (kb + j > qrow) s[m][c][j] = -1e30f;
                }
            }
        }

#pragma unroll
        for (int m = 0; m < 2; ++m) {
            // row-max: in-reg tree (16 vals, one q-row) + 2 cross-lane hops
            float t0 = fmaxf(fmaxf(s[m][0][0], s[m][0][1]), fmaxf(s[m][0][2], s[m][0][3]));
            float t1 = fmaxf(fmaxf(s[m][1][0], s[m][1][1]), fmaxf(s[m][1][2], s[m][1][3]));
            float t2 = fmaxf(fmaxf(s[m][2][0], s[m][2][1]), fmaxf(s[m][2][2], s[m][2][3]));
            float t3 = fmaxf(fmaxf(s[m][3][0], s[m][3][1]), fmaxf(s[m][3][2], s[m][3][3]));
            float pm = fmaxf(fmaxf(t0, t1), fmaxf(t2, t3));
            pm = fmaxf(pm, __shfl_xor(pm, 16));
            pm = fmaxf(pm, __shfl_xor(pm, 32));

            // defer-max: rescale only when max grew materially (log2 domain)
            if (__any(pm > mrow[m] + 11.0f)) {
                const float mnew = fmaxf(mrow[m], pm);
                const float fac  = exp2f(mrow[m] - mnew);
                mrow[m] = mnew;
                lrow[m] *= fac;
#pragma unroll
                for (int n = 0; n < 4; ++n) o[m][n] *= fac;
            }

            float p[4][4];
#pragma unroll
            for (int c = 0; c < 4; ++c)
#pragma unroll
                for (int j = 0; j < 4; ++j)
                    p[c][j] = exp2f(s[m][c][j] - mrow[m]);

            float u0 = (p[0][0] + p[0][1]) + (p[0][2] + p[0][3]);
            float u1 = (p[1][0] + p[1][1]) + (p[1][2] + p[1][3]);
            float u2 = (p[2][0] + p[2][1]) + (p[2][2] + p[2][3]);
            float u3 = (p[3][0] + p[3][1]) + (p[3][2] + p[3][3]);
            float ps = (u0 + u1) + (u2 + u3);
            ps += __shfl_xor(ps, 16);
            ps += __shfl_xor(ps, 32);
            lrow[m] += ps;

            // pack P row-fragment: 4 bf16 per c -> swizzled ds_write_b64
#pragma unroll
            for (int c = 0; c < 4; ++c) {
                ushort4 pk4;
                pk4.x = f2bf(p[c][0]); pk4.y = f2bf(p[c][1]);
                pk4.z = f2bf(p[c][2]); pk4.w = f2bf(p[c][3]);
                *reinterpret_cast<ushort4*>(&Ps[w][m][r][(16*c + 4*g) ^ swz]) = pk4;
            }
        }

        // P fragments (swizzled b128 reads) + PV as mfma(V^T, P^T)
        bf16x8 pf[2][2];
#pragma unroll
        for (int m = 0; m < 2; ++m)
#pragma unroll
            for (int hh = 0; hh < 2; ++hh)
                pf[m][hh] = *reinterpret_cast<const bf16x8*>(
                    &Ps[w][m][r][(32*hh + 8*g) ^ swz]);

#pragma unroll
        for (int n = 0; n < 4; ++n) {
            bf16x8 vf0 = *reinterpret_cast<const bf16x8*>(
                Vh + (size_t)(16*n + r) * SEQL + key0 + 8*g);
            bf16x8 vf1 = *reinterpret_cast<const bf16x8*>(
                Vh + (size_t)(16*n + r) * SEQL + key0 + 32 + 8*g);
#pragma unroll
            for (int m = 0; m < 2; ++m) {
                o[m][n] = mfma16(vf0, pf[m][0], o[m][n]);
                o[m][n] = mfma16(vf1, pf[m][1], o[m][n]);
            }
        }
    }

    // epilogue: O^T fragment -> ctx row-major; per-lane row, 8B packed stores
#pragma unroll
    for (int m = 0; m < 2; ++m) {
        const float inv = 1.0f / lrow[m];
        const size_t rowbase = (size_t)(b*SEQL + qb + 16*m + r) * DOUT + h*HDIM;
#pragma unroll
        for (int n = 0; n < 4; ++n) {
            ushort4 ov;
            ov.x = f2bf(o[m][n][0] * inv); ov.y = f2bf(o[m][n][1] * inv);
            ov.z = f2bf(o[m][n][2] * inv); ov.w = f2bf(o[m][n][3] * inv);
            *reinterpret_cast<ushort4*>(&ctx[rowbase + 16*n + 4*g]) = ov;
        }
    }
}

extern "C" void kernel_launch(void* const* d_in, const int* in_sizes, int n_in,
                              void* d_out, int out_size, void* d_ws, size_t ws_size,
                              hipStream_t stream) {
    const float* x  = (const float*)d_in[0];
    const float* Wq = (const float*)d_in[1];
    const float* bq = (const float*)d_in[2];
    const float* Wk = (const float*)d_in[3];
    const float* bk = (const float*)d_in[4];
    const float* Wv = (const float*)d_in[5];
    const float* bv = (const float*)d_in[6];
    const float* Wo = (const float*)d_in[7];
    const float* bo = (const float*)d_in[8];
    float* out = (float*)d_out;
    (void)in_sizes; (void)n_in; (void)out_size; (void)ws_size;

    char* ws = (char*)d_ws;
    __hip_bfloat16* xb  = (__hip_bfloat16*)ws;                       // 16 MB
    __hip_bfloat16* Wt3 = (__hip_bfloat16*)(ws + (16u << 20));       // 6 MB (Q,K,V slabs)
    __hip_bfloat16* Wot = (__hip_bfloat16*)(ws + (22u << 20));       // 2 MB
    __hip_bfloat16* Qb  = (__hip_bfloat16*)(ws + (24u << 20));       // 16 MB
    __hip_bfloat16* Kb  = Qb + (size_t)MTOT * DOUT;                  // 16 MB
    __hip_bfloat16* Vtb = Kb + (size_t)MTOT * DOUT;                  // 16 MB
    __hip_bfloat16* ctx = xb;  // alias: xb dead after the QKV GEMMs

    cvt_bf16<<<2048, 256, 0, stream>>>((const float4*)x, (ushort4*)xb, MTOT * DIN / 4);

    dim3 tb(32, 8);
    transpose_cvt3<<<dim3(32, 32, 3), tb, 0, stream>>>(Wq, Wk, Wv, Wt3);
    transpose_cvt <<<dim3(32, 32),    tb, 0, stream>>>(Wo, Wot);

    // QK fused GEMM (N=2048, swapped orientation). Q scale folds 1/8 * log2(e).
    dim3 gqk(2*DOUT / 128, MTOT / 128);  // (16, 64)
    gemm_mfma<0><<<gqk, 256, 0, stream>>>(xb, Wt3, bq, bk, Qb, Kb,
                                          0.125f * 1.44269504088896f);
    // V GEMM (N=1024, normal orientation) -> V^T
    dim3 gv(DOUT / 128, MTOT / 128);     // (8, 64)
    gemm_mfma<1><<<gv, 256, 0, stream>>>(xb, Wt3 + (size_t)2*DOUT*DIN, bv, nullptr,
                                         Vtb, nullptr, 1.0f);

    dim3 ag(16, BSZ * NHEAD);  // 64 strips / 4 waves = 16 blocks x 64 (b,h)
    attn_fwd<<<ag, 256, 0, stream>>>(Qb, Kb, Vtb, ctx);

    // out-proj (swapped orientation, f32x4 stores)
    gemm_mfma<2><<<gv, 256, 0, stream>>>(ctx, Wot, bo, nullptr,
                                         out, nullptr, 1.0f);
}

// Round 9
// 305.238 us; speedup vs baseline: 2.2020x; 1.3508x over previous
//
#include <hip/hip_runtime.h>
#include <hip/hip_bf16.h>
#include <stdint.h>

#define DIN   1024
#define DOUT  1024
#define NHEAD 16
#define HDIM  64
#define SEQL  2048
#define BSZ   4
#define MTOT  (BSZ*SEQL)   // 8192
#define KDIM  1024

typedef __bf16 bf16x8 __attribute__((ext_vector_type(8)));
typedef float  f32x4  __attribute__((ext_vector_type(4)));

__device__ __forceinline__ f32x4 mfma16(bf16x8 a, bf16x8 b, f32x4 c) {
    return __builtin_amdgcn_mfma_f32_16x16x32_bf16(a, b, c, 0, 0, 0);
}

__device__ __forceinline__ void gl_lds16(const void* gsrc, void* ldst) {
    __builtin_amdgcn_global_load_lds(
        (const __attribute__((address_space(1))) uint32_t*)gsrc,
        (__attribute__((address_space(3))) uint32_t*)ldst, 16, 0, 0);
}

__device__ __forceinline__ unsigned short f2bf(float f) {
    union { __hip_bfloat16 h; unsigned short u; } cv;
    cv.h = __float2bfloat16(f);
    return cv.u;
}

// ---------------- fp32 -> bf16 elementwise (vectorized) ----------------
__global__ void cvt_bf16(const float4* __restrict__ in, ushort4* __restrict__ out, int n4) {
    int idx = blockIdx.x * blockDim.x + threadIdx.x;
    int stride = gridDim.x * blockDim.x;
    for (int i = idx; i < n4; i += stride) {
        float4 v = in[i];
        ushort4 o;
        o.x = f2bf(v.x); o.y = f2bf(v.y); o.z = f2bf(v.z); o.w = f2bf(v.w);
        out[i] = o;
    }
}

// ---- transpose + convert 3x W[1024][1024] f32 -> one Wt3[3072][1024] bf16 ----
__global__ void transpose_cvt3(const float* __restrict__ W0, const float* __restrict__ W1,
                               const float* __restrict__ W2, __hip_bfloat16* __restrict__ Wt3) {
    __shared__ __hip_bfloat16 t[32][33];
    const int tx = threadIdx.x, ty = threadIdx.y;   // (32, 8)
    const int bx = blockIdx.x, by = blockIdx.y, z = blockIdx.z;
    const float* W = (z == 0) ? W0 : (z == 1) ? W1 : W2;
    __hip_bfloat16* Wt = Wt3 + (size_t)z * DOUT * DIN;
#pragma unroll
    for (int r = 0; r < 4; ++r)
        t[ty + 8*r][tx] = __float2bfloat16(W[(size_t)(by*32 + ty + 8*r) * DOUT + bx*32 + tx]);
    __syncthreads();
#pragma unroll
    for (int r = 0; r < 4; ++r)
        Wt[(size_t)(bx*32 + ty + 8*r) * DIN + by*32 + tx] = t[tx][ty + 8*r];
}

__global__ void transpose_cvt(const float* __restrict__ W, __hip_bfloat16* __restrict__ Wt) {
    __shared__ __hip_bfloat16 t[32][33];
    const int tx = threadIdx.x, ty = threadIdx.y;
    const int bx = blockIdx.x, by = blockIdx.y;
#pragma unroll
    for (int r = 0; r < 4; ++r)
        t[ty + 8*r][tx] = __float2bfloat16(W[(size_t)(by*32 + ty + 8*r) * DOUT + bx*32 + tx]);
    __syncthreads();
#pragma unroll
    for (int r = 0; r < 4; ++r)
        Wt[(size_t)(bx*32 + ty + 8*r) * DIN + by*32 + tx] = t[tx][ty + 8*r];
}

// ---------------- 128x128-tile MFMA GEMM (256 threads, 4 waves, BK=32) ----------------
// EPI 0 (QK, swapped mfma -> C^T fragments, packed 8B stores)
// EPI 1 (V, normal mfma -> V^T packed seq stores)
// EPI 2 (out-proj, swapped mfma, packed 16B f32 stores)
// NOTE: 256-thread blocks only (512-thread blocks get a 128-VGPR budget, R5-R7).
template <int EPI>
__global__ __launch_bounds__(256)
void gemm_mfma(const __hip_bfloat16* __restrict__ A,
               const __hip_bfloat16* __restrict__ Bt,
               const float* __restrict__ b0, const float* __restrict__ b1,
               void* __restrict__ o0, void* __restrict__ o1,
               float scale)
{
    __shared__ alignas(16) __hip_bfloat16 As[2][4][128][8];
    __shared__ alignas(16) __hip_bfloat16 Bs[2][4][128][8];

    const int tid  = threadIdx.x;
    const int w    = tid >> 6;
    const int lane = tid & 63;
    const int g    = lane >> 4;
    const int r    = lane & 15;
    const int wr   = w >> 1, wc = w & 1;

    const int row0 = blockIdx.y * 128;
    const int col0 = blockIdx.x * 128;

    f32x4 acc[4][4];
#pragma unroll
    for (int m = 0; m < 4; ++m)
#pragma unroll
        for (int n = 0; n < 4; ++n) acc[m][n] = (f32x4)0.0f;

    auto stage = [&](int buf, int kt) {
        const __hip_bfloat16* ga = A  + (size_t)(row0 + lane) * KDIM + kt*32 + 8*w;
        const __hip_bfloat16* gb = Bt + (size_t)(col0 + lane) * KDIM + kt*32 + 8*w;
        gl_lds16(ga,            &As[buf][w][0][0]);
        gl_lds16(ga + 64*KDIM,  &As[buf][w][64][0]);
        gl_lds16(gb,            &Bs[buf][w][0][0]);
        gl_lds16(gb + 64*KDIM,  &Bs[buf][w][64][0]);
    };

    stage(0, 0);
    __syncthreads();

    const int NKT = KDIM / 32;
    for (int kt = 0; kt < NKT; ++kt) {
        const int cur = kt & 1;
        if (kt + 1 < NKT) stage(cur ^ 1, kt + 1);

        bf16x8 af[4], bfr[4];
#pragma unroll
        for (int m = 0; m < 4; ++m)
            af[m] = *reinterpret_cast<const bf16x8*>(&As[cur][g][64*wr + 16*m + r][0]);
#pragma unroll
        for (int n = 0; n < 4; ++n)
            bfr[n] = *reinterpret_cast<const bf16x8*>(&Bs[cur][g][64*wc + 16*n + r][0]);

#pragma unroll
        for (int m = 0; m < 4; ++m)
#pragma unroll
            for (int n = 0; n < 4; ++n) {
                if (EPI == 1) acc[m][n] = mfma16(af[m], bfr[n], acc[m][n]);  // C
                else          acc[m][n] = mfma16(bfr[n], af[m], acc[m][n]);  // C^T
            }

        __syncthreads();
    }

    if (EPI == 0) {
        const int slab = col0 >> 10;                    // block-uniform
        const float* bp = (slab == 0) ? b0 : b1;
        __hip_bfloat16* op = (__hip_bfloat16*)((slab == 0) ? o0 : o1);
        const float sc = (slab == 0) ? scale : 1.0f;
#pragma unroll
        for (int m = 0; m < 4; ++m) {
            const int rowg = row0 + 64*wr + 16*m + r;
            const int bb = rowg >> 11, sq = rowg & (SEQL-1);
#pragma unroll
            for (int n = 0; n < 4; ++n) {
                const int c2 = (col0 & 1023) + 64*wc + 16*n + 4*g;
                const int hh = c2 >> 6, dd = c2 & (HDIM-1);
                const float4 bv4 = *reinterpret_cast<const float4*>(&bp[c2]);
                ushort4 ov;
                ov.x = f2bf((acc[m][n][0] + bv4.x) * sc);
                ov.y = f2bf((acc[m][n][1] + bv4.y) * sc);
                ov.z = f2bf((acc[m][n][2] + bv4.z) * sc);
                ov.w = f2bf((acc[m][n][3] + bv4.w) * sc);
                *reinterpret_cast<ushort4*>(
                    &op[(((size_t)(bb*NHEAD + hh) * SEQL + sq) << 6) + dd]) = ov;
            }
        }
    } else if (EPI == 1) {
#pragma unroll
        for (int n = 0; n < 4; ++n) {
            const int colg = col0 + 64*wc + 16*n + r;
            const int hh = colg >> 6, dd = colg & (HDIM-1);
            const float bv_ = b0[colg];
#pragma unroll
            for (int m = 0; m < 4; ++m) {
                const int rowg0 = row0 + 64*wr + 16*m + 4*g;
                const int bb = rowg0 >> 11, sq0 = rowg0 & (SEQL-1);
                ushort4 ov;
                ov.x = f2bf(acc[m][n][0] + bv_);
                ov.y = f2bf(acc[m][n][1] + bv_);
                ov.z = f2bf(acc[m][n][2] + bv_);
                ov.w = f2bf(acc[m][n][3] + bv_);
                *reinterpret_cast<ushort4*>(
                    &((__hip_bfloat16*)o0)[((size_t)(bb*NHEAD + hh) * HDIM + dd) * SEQL + sq0]) = ov;
            }
        }
    } else {
#pragma unroll
        for (int m = 0; m < 4; ++m) {
            const int rowg = row0 + 64*wr + 16*m + r;
#pragma unroll
            for (int n = 0; n < 4; ++n) {
                const int colg0 = col0 + 64*wc + 16*n + 4*g;
                const float4 bv4 = *reinterpret_cast<const float4*>(&b0[colg0]);
                float4 ov;
                ov.x = acc[m][n][0] + bv4.x;
                ov.y = acc[m][n][1] + bv4.y;
                ov.z = acc[m][n][2] + bv4.z;
                ov.w = acc[m][n][3] + bv4.w;
                *reinterpret_cast<float4*>(&((float*)o0)[(size_t)rowg * DOUT + colg0]) = ov;
            }
        }
    }
}

// ---------------- causal flash attention (R3 structure + reg pipeline) ----------------
// Q,K: [B,H,S,64] bf16 (Q pre-scaled by log2e/8).  Vt: [B,H,64,S] bf16.
// ctx: [B,S,H*64] bf16.
// 4 waves/block, 32 rows/wave, strip pair (sp, 63-sp), grid (8,64) -- proven R3 shape.
// NEW: V issued at top of each step (hidden under QK+softmax); K double-buffered
// across steps via 2x-unrolled loop with static kA/kB (T14-style); setprio on MFMA.
__global__ __launch_bounds__(256)
void attn_fwd(const __hip_bfloat16* __restrict__ Q,
              const __hip_bfloat16* __restrict__ K,
              const __hip_bfloat16* __restrict__ Vt,
              __hip_bfloat16* __restrict__ ctx)
{
    __shared__ alignas(16) __hip_bfloat16 Ps[4][2][16][64];

    const int tid  = threadIdx.x;
    const int w    = tid >> 6;
    const int lane = tid & 63;
    const int g    = lane >> 4;
    const int r    = lane & 15;
    const int swz  = (r & 7) << 3;   // element-XOR within a 64-elt (128B) row

    const int bh = blockIdx.y;
    const int b  = bh >> 4, h = bh & 15;

    const __hip_bfloat16* Qh = Q  + (size_t)bh * SEQL * HDIM;
    const __hip_bfloat16* Kh = K  + (size_t)bh * SEQL * HDIM;
    const __hip_bfloat16* Vh = Vt + (size_t)bh * HDIM * SEQL;

    const int sp = blockIdx.x * 4 + w;   // 0..31

#pragma unroll 1
    for (int ti = 0; ti < 2; ++ti) {
        const int strip = ti ? (63 - sp) : sp;
        const int qb = strip * 32;

        bf16x8 qf[2][2];
#pragma unroll
        for (int m = 0; m < 2; ++m)
#pragma unroll
            for (int hh = 0; hh < 2; ++hh)
                qf[m][hh] = *reinterpret_cast<const bf16x8*>(
                    Qh + (size_t)(qb + 16*m + r) * HDIM + 32*hh + 8*g);

        f32x4 o[2][4];
        float mrow[2], lrow[2];
#pragma unroll
        for (int m = 0; m < 2; ++m) {
#pragma unroll
            for (int n = 0; n < 4; ++n) o[m][n] = (f32x4)0.0f;
            mrow[m] = -1e30f; lrow[m] = 0.0f;
        }

        const int nst = ((qb + 31) >> 6) + 1;

        bf16x8 kA[4][2], kB[4][2], vf[4][2];

        auto loadK = [&](bf16x8 (&kf)[4][2], int key0) __attribute__((always_inline)) {
#pragma unroll
            for (int c = 0; c < 4; ++c)
#pragma unroll
                for (int hh = 0; hh < 2; ++hh)
                    kf[c][hh] = *reinterpret_cast<const bf16x8*>(
                        Kh + (size_t)(key0 + 16*c + r) * HDIM + 32*hh + 8*g);
        };

        auto step = [&](bf16x8 (&KC)[4][2], bf16x8 (&KN)[4][2], int kt)
                        __attribute__((always_inline)) {
            const int key0 = kt * 64;

            // V for THIS step: issued first, consumed after softmax (~40 VALU ops later)
#pragma unroll
            for (int n = 0; n < 4; ++n) {
                vf[n][0] = *reinterpret_cast<const bf16x8*>(
                    Vh + (size_t)(16*n + r) * SEQL + key0 + 8*g);
                vf[n][1] = *reinterpret_cast<const bf16x8*>(
                    Vh + (size_t)(16*n + r) * SEQL + key0 + 32 + 8*g);
            }
            // K for NEXT step: in flight across the whole step
            if (kt + 1 < nst) loadK(KN, key0 + 64);

            // S^T[key = key0+16c+4g+j][qrow = qb+16m+r]
            f32x4 s[2][4];
            __builtin_amdgcn_s_setprio(1);
#pragma unroll
            for (int m = 0; m < 2; ++m)
#pragma unroll
                for (int c = 0; c < 4; ++c) {
                    f32x4 t = (f32x4)0.0f;
                    t = mfma16(KC[c][0], qf[m][0], t);
                    t = mfma16(KC[c][1], qf[m][1], t);
                    s[m][c] = t;
                }
            __builtin_amdgcn_s_setprio(0);

            if (kt == nst - 1) {   // causal mask only in the boundary step
#pragma unroll
                for (int m = 0; m < 2; ++m) {
                    const int qrow = qb + 16*m + r;
#pragma unroll
                    for (int c = 0; c < 4; ++c) {
                        const int kb = key0 + 16*c + 4*g;
#pragma unroll
                        for (int j = 0; j < 4; ++j)
                            if (kb + j > qrow) s[m][c][j] = -1e30f;
                    }
                }
            }

#pragma unroll
            for (int m = 0; m < 2; ++m) {
                // row-max: in-reg tree (16 vals, one q-row) + 2 cross-lane hops
                float t0 = fmaxf(fmaxf(s[m][0][0], s[m][0][1]), fmaxf(s[m][0][2], s[m][0][3]));
                float t1 = fmaxf(fmaxf(s[m][1][0], s[m][1][1]), fmaxf(s[m][1][2], s[m][1][3]));
                float t2 = fmaxf(fmaxf(s[m][2][0], s[m][2][1]), fmaxf(s[m][2][2], s[m][2][3]));
                float t3 = fmaxf(fmaxf(s[m][3][0], s[m][3][1]), fmaxf(s[m][3][2], s[m][3][3]));
                float pm = fmaxf(fmaxf(t0, t1), fmaxf(t2, t3));
                pm = fmaxf(pm, __shfl_xor(pm, 16));
                pm = fmaxf(pm, __shfl_xor(pm, 32));

                // defer-max: rescale only when max grew materially (log2 domain)
                if (__any(pm > mrow[m] + 11.0f)) {
                    const float mnew = fmaxf(mrow[m], pm);
                    const float fac  = exp2f(mrow[m] - mnew);
                    mrow[m] = mnew;
                    lrow[m] *= fac;
#pragma unroll
                    for (int n = 0; n < 4; ++n) o[m][n] *= fac;
                }

                float p[4][4];
#pragma unroll
                for (int c = 0; c < 4; ++c)
#pragma unroll
                    for (int j = 0; j < 4; ++j)
                        p[c][j] = exp2f(s[m][c][j] - mrow[m]);

                float u0 = (p[0][0] + p[0][1]) + (p[0][2] + p[0][3]);
                float u1 = (p[1][0] + p[1][1]) + (p[1][2] + p[1][3]);
                float u2 = (p[2][0] + p[2][1]) + (p[2][2] + p[2][3]);
                float u3 = (p[3][0] + p[3][1]) + (p[3][2] + p[3][3]);
                float ps = (u0 + u1) + (u2 + u3);
                ps += __shfl_xor(ps, 16);
                ps += __shfl_xor(ps, 32);
                lrow[m] += ps;

                // pack P row-fragment: 4 bf16 per c -> swizzled ds_write_b64
#pragma unroll
                for (int c = 0; c < 4; ++c) {
                    ushort4 pk4;
                    pk4.x = f2bf(p[c][0]); pk4.y = f2bf(p[c][1]);
                    pk4.z = f2bf(p[c][2]); pk4.w = f2bf(p[c][3]);
                    *reinterpret_cast<ushort4*>(&Ps[w][m][r][(16*c + 4*g) ^ swz]) = pk4;
                }
            }

            // P fragments (swizzled b128 reads) + PV as mfma(V^T, P^T)
            bf16x8 pf[2][2];
#pragma unroll
            for (int m = 0; m < 2; ++m)
#pragma unroll
                for (int hh = 0; hh < 2; ++hh)
                    pf[m][hh] = *reinterpret_cast<const bf16x8*>(
                        &Ps[w][m][r][(32*hh + 8*g) ^ swz]);

            __builtin_amdgcn_s_setprio(1);
#pragma unroll
            for (int n = 0; n < 4; ++n)
#pragma unroll
                for (int m = 0; m < 2; ++m) {
                    o[m][n] = mfma16(vf[n][0], pf[m][0], o[m][n]);
                    o[m][n] = mfma16(vf[n][1], pf[m][1], o[m][n]);
                }
            __builtin_amdgcn_s_setprio(0);
        };

        loadK(kA, 0);
        int kt = 0;
        while (true) {
            step(kA, kB, kt); if (++kt >= nst) break;
            step(kB, kA, kt); if (++kt >= nst) break;
        }

        // epilogue: O^T fragment -> ctx row-major; per-lane row, 8B packed stores
#pragma unroll
        for (int m = 0; m < 2; ++m) {
            const float inv = 1.0f / lrow[m];
            const size_t rowbase = (size_t)(b*SEQL + qb + 16*m + r) * DOUT + h*HDIM;
#pragma unroll
            for (int n = 0; n < 4; ++n) {
                ushort4 ov;
                ov.x = f2bf(o[m][n][0] * inv); ov.y = f2bf(o[m][n][1] * inv);
                ov.z = f2bf(o[m][n][2] * inv); ov.w = f2bf(o[m][n][3] * inv);
                *reinterpret_cast<ushort4*>(&ctx[rowbase + 16*n + 4*g]) = ov;
            }
        }
    }
}

extern "C" void kernel_launch(void* const* d_in, const int* in_sizes, int n_in,
                              void* d_out, int out_size, void* d_ws, size_t ws_size,
                              hipStream_t stream) {
    const float* x  = (const float*)d_in[0];
    const float* Wq = (const float*)d_in[1];
    const float* bq = (const float*)d_in[2];
    const float* Wk = (const float*)d_in[3];
    const float* bk = (const float*)d_in[4];
    const float* Wv = (const float*)d_in[5];
    const float* bv = (const float*)d_in[6];
    const float* Wo = (const float*)d_in[7];
    const float* bo = (const float*)d_in[8];
    float* out = (float*)d_out;
    (void)in_sizes; (void)n_in; (void)out_size; (void)ws_size;

    char* ws = (char*)d_ws;
    __hip_bfloat16* xb  = (__hip_bfloat16*)ws;                       // 16 MB
    __hip_bfloat16* Wt3 = (__hip_bfloat16*)(ws + (16u << 20));       // 6 MB (Q,K,V slabs)
    __hip_bfloat16* Wot = (__hip_bfloat16*)(ws + (22u << 20));       // 2 MB
    __hip_bfloat16* Qb  = (__hip_bfloat16*)(ws + (24u << 20));       // 16 MB
    __hip_bfloat16* Kb  = Qb + (size_t)MTOT * DOUT;                  // 16 MB
    __hip_bfloat16* Vtb = Kb + (size_t)MTOT * DOUT;                  // 16 MB
    __hip_bfloat16* ctx = xb;  // alias: xb dead after the QKV GEMMs

    cvt_bf16<<<2048, 256, 0, stream>>>((const float4*)x, (ushort4*)xb, MTOT * DIN / 4);

    dim3 tb(32, 8);
    transpose_cvt3<<<dim3(32, 32, 3), tb, 0, stream>>>(Wq, Wk, Wv, Wt3);
    transpose_cvt <<<dim3(32, 32),    tb, 0, stream>>>(Wo, Wot);

    // QK fused GEMM (N=2048, swapped orientation). Q scale folds 1/8 * log2(e).
    dim3 gqk(2*DOUT / 128, MTOT / 128);  // (16, 64)
    gemm_mfma<0><<<gqk, 256, 0, stream>>>(xb, Wt3, bq, bk, Qb, Kb,
                                          0.125f * 1.44269504088896f);
    // V GEMM (N=1024, normal orientation) -> V^T
    dim3 gv(DOUT / 128, MTOT / 128);     // (8, 64)
    gemm_mfma<1><<<gv, 256, 0, stream>>>(xb, Wt3 + (size_t)2*DOUT*DIN, bv, nullptr,
                                         Vtb, nullptr, 1.0f);

    dim3 ag(8, BSZ * NHEAD);  // 32 strip-pairs per bh / 4 waves = 8 blocks x 64 (b,h)
    attn_fwd<<<ag, 256, 0, stream>>>(Qb, Kb, Vtb, ctx);

    // out-proj (swapped orientation, f32x4 stores)
    gemm_mfma<2><<<gv, 256, 0, stream>>>(ctx, Wot, bo, nullptr,
                                         out, nullptr, 1.0f);
}